// Round 1
// baseline (1768.701 us; speedup 1.0000x reference)
//
#include <hip/hip_runtime.h>

// noiseRNN: h_t = tanh(x_t @ w_ih.T + b_ih + h_{t-1} @ w_hh.T + b_hh)
//           out_t = h_t ; carry = h_t + 0.1*noise_t
// T=2048 B=256 I=64 H=128, fp32.
// Grid = 256 (one workgroup per batch element, fully independent recurrences).
// Block = 256 threads = 4 waves; K(=192 augmented) split 4-way across waves,
// each thread owns 2 output rows (h2, h2+64) x 48-wide weight slice in VGPRs.

constexpr int T_ = 2048;
constexpr int B_ = 256;
constexpr int I_ = 64;
constexpr int H_ = 128;
constexpr int BH_ = B_ * H_;     // 32768
constexpr int BI_ = B_ * I_;     // 16384
constexpr long long TBH_ = (long long)T_ * BH_;  // 67108864
constexpr float STD_ = 0.1f;
constexpr int AUG_ = H_ + I_;    // 192 augmented K dim
constexpr int JPT_ = AUG_ / 4;   // 48 K-elems per wave-slice

__global__ __launch_bounds__(256)
void rnn_scan(const float* __restrict__ x, const float* __restrict__ w_ih,
              const float* __restrict__ w_hh, const float* __restrict__ b_ih,
              const float* __restrict__ b_hh, const float* __restrict__ noise,
              const float* __restrict__ h0, float* __restrict__ out)
{
    __shared__ float aug[2][AUG_];     // [h_prev(+noise) | x_t], double-buffered
    __shared__ float part[4 * 132];    // per-wave partial sums, stride 132 (conflict-free)

    const int b   = blockIdx.x;
    const int tid = threadIdx.x;
    const int q   = tid >> 6;          // wave id = K-slice id
    const int h2  = tid & 63;          // output rows h2 and h2+64
    const int j0  = q * JPT_;

    // ---- augmented weight slices into registers (96 VGPRs) ----
    float W0[JPT_], W1[JPT_];
#pragma unroll
    for (int jj = 0; jj < JPT_; ++jj) {
        const int j = j0 + jj;
        if (j < H_) {
            W0[jj] = w_hh[h2 * H_ + j];
            W1[jj] = w_hh[(h2 + 64) * H_ + j];
        } else {
            W0[jj] = w_ih[h2 * I_ + (j - H_)];
            W1[jj] = w_ih[(h2 + 64) * I_ + (j - H_)];
        }
    }

    float bias = 0.0f;
    if (tid < H_) bias = b_ih[tid] + b_hh[tid];

    // ---- init state buffer 0: h_prev from hidden_in, x for t=0 ----
    if (tid < H_) aug[0][tid] = h0[b * H_ + tid];
    if (tid < I_) aug[0][H_ + tid] = x[b * I_ + tid];
    __syncthreads();

    int p = 0;
    for (int t = 0; t < T_; ++t) {
        // prefetch noise (this step) and x (next step) while we compute
        float nv = 0.0f, xv = 0.0f;
        if (tid < H_) nv = noise[(long long)t * BH_ + b * H_ + tid];
        if (tid < I_ && (t + 1) < T_) xv = x[(long long)(t + 1) * BI_ + b * I_ + tid];

        // ---- dot over this wave's K-slice (broadcast float4 LDS reads) ----
        float p0 = 0.0f, p1 = 0.0f;
        const float* ap = &aug[p][j0];
#pragma unroll
        for (int i = 0; i < JPT_ / 4; ++i) {
            const float4 v = *(const float4*)(ap + 4 * i);
            p0 = fmaf(v.x, W0[4 * i + 0], p0);  p1 = fmaf(v.x, W1[4 * i + 0], p1);
            p0 = fmaf(v.y, W0[4 * i + 1], p0);  p1 = fmaf(v.y, W1[4 * i + 1], p1);
            p0 = fmaf(v.z, W0[4 * i + 2], p0);  p1 = fmaf(v.z, W1[4 * i + 2], p1);
            p0 = fmaf(v.w, W0[4 * i + 3], p0);  p1 = fmaf(v.w, W1[4 * i + 3], p1);
        }
        part[q * 132 + h2]      = p0;
        part[q * 132 + h2 + 64] = p1;
        __syncthreads();   // barrier A: partials visible; aug[p] reads all done

        const int np = p ^ 1;
        if (tid < H_) {
            const float s = part[tid] + part[132 + tid] + part[264 + tid]
                          + part[396 + tid] + bias;
            const float hn = tanhf(s);
            out[(long long)t * BH_ + b * H_ + tid] = hn;
            const float hnx = fmaf(STD_, nv, hn);     // carried state gets noise
            aug[np][tid] = hnx;
            if (t == T_ - 1) out[TBH_ + b * H_ + tid] = hnx;  // h_last
        }
        if (tid < I_) aug[np][H_ + tid] = xv;
        __syncthreads();   // barrier B: next-state buffer complete
        p = np;
    }
}

extern "C" void kernel_launch(void* const* d_in, const int* in_sizes, int n_in,
                              void* d_out, int out_size, void* d_ws, size_t ws_size,
                              hipStream_t stream) {
    const float* x     = (const float*)d_in[0];
    const float* w_ih  = (const float*)d_in[1];
    const float* w_hh  = (const float*)d_in[2];
    const float* b_ih  = (const float*)d_in[3];
    const float* b_hh  = (const float*)d_in[4];
    const float* noise = (const float*)d_in[5];
    const float* h0    = (const float*)d_in[6];
    float* outp        = (float*)d_out;

    rnn_scan<<<dim3(B_), dim3(256), 0, stream>>>(x, w_ih, w_hh, b_ih, b_hh,
                                                 noise, h0, outp);
}